// Round 1
// baseline (145.511 us; speedup 1.0000x reference)
//
#include <hip/hip_runtime.h>
#include <hip/hip_bf16.h>

// Non-backtracking random walk.
// walks: [steps+1, n] int32 ; walk_edges: [steps, n] int32, concatenated in d_out.
// One thread per walk; 32 sequential steps per thread.
//
// Chain-shortening: always gather BOTH adj_nodes[chosen] and adj_nodes[alt]
// (independent loads, issued back-to-back) and select after, instead of a
// divergent second gather (P(wave has a backtracker) ~ 98%, which would make
// the dependent chain 2 adj_nodes latencies per step).
__global__ __launch_bounds__(256) void walker_kernel(
    const int* __restrict__ adj_nodes,
    const int* __restrict__ adj_offset,
    const int* __restrict__ degrees,
    const int* __restrict__ choices,
    int* __restrict__ out, int n, int steps) {

    int w = blockIdx.x * blockDim.x + threadIdx.x;
    if (w >= n) return;

    int* walks      = out;                   // [steps+1, n]
    int* walk_edges = out + (steps + 1) * n; // [steps, n]

    int prev = -1;
    int cur  = w;
    walks[w] = w;  // walks[0, w] = start

    for (int i = 0; i < steps; ++i) {
        int ch  = choices[i * n + w];        // coalesced
        int deg = degrees[cur];              // gather, 400KB array (L2-hot)
        int off = adj_offset[cur];           // gather, 400KB array (L2-hot)
        int nb  = deg - 1 > 1 ? deg - 1 : 1;

        int edge_idx = ch % deg;             // ch >= 0 so C % == python % here
        int chosen   = off + edge_idx;
        int alt      = off + (edge_idx + 1 + ch % nb) % deg;

        // issue both gathers in parallel (no dependence between them)
        int nw0 = adj_nodes[chosen];
        int nw1 = adj_nodes[alt];

        bool bt = (nw0 == prev);
        int nw       = bt ? nw1 : nw0;
        int chosen_f = bt ? alt : chosen;

        walks[(i + 1) * n + w] = nw;         // coalesced store
        walk_edges[i * n + w]  = chosen_f;   // coalesced store

        prev = cur;
        cur  = nw;
    }
}

extern "C" void kernel_launch(void* const* d_in, const int* in_sizes, int n_in,
                              void* d_out, int out_size, void* d_ws, size_t ws_size,
                              hipStream_t stream) {
    // inputs: 0=x (float32, UNUSED by reference), 1=adj_nodes, 2=adj_offset,
    //         3=degrees, 4=choices
    const int* adj_nodes  = (const int*)d_in[1];
    const int* adj_offset = (const int*)d_in[2];
    const int* degrees    = (const int*)d_in[3];
    const int* choices    = (const int*)d_in[4];
    int* out = (int*)d_out;

    int n     = in_sizes[2];          // N_NODES
    int steps = in_sizes[4] / n;      // STEPS

    int block = 256;
    int grid  = (n + block - 1) / block;
    walker_kernel<<<grid, block, 0, stream>>>(adj_nodes, adj_offset, degrees,
                                              choices, out, n, steps);
}

// Round 2
// 118.557 us; speedup vs baseline: 1.2273x; 1.2273x over previous
//
#include <hip/hip_runtime.h>
#include <hip/hip_bf16.h>

// Non-backtracking random walk, one thread per walk, 32 sequential steps.
// out = [walks (steps+1,n) ; walk_edges (steps,n)] as int32.
//
// Optimization: the problem's CSR is uniform (degrees[v]==16,
// adj_offset[v]==16*v). A check kernel verifies this and sets a flag in d_ws;
// the walker takes a fast path (deg/offset in pure VALU -> dependent chain is
// ONE gather per step instead of two) or a fully-general fallback.
// chosen & alt always lie in the same 64B adjacency row -> one cache line.

#define DEG 16

__global__ void check_kernel(const int* __restrict__ degrees,
                             const int* __restrict__ adj_offset,
                             int n, int* __restrict__ flag) {
    int v = blockIdx.x * blockDim.x + threadIdx.x;
    if (v < n) {
        if (degrees[v] != DEG || adj_offset[v] != v * DEG)
            atomicOr(flag, 1);   // only executes on violation -> no contention
    }
}

template <int STEPS>
__global__ __launch_bounds__(256) void walker_fast(
    const int* __restrict__ adj_nodes,
    const int* __restrict__ adj_offset,
    const int* __restrict__ degrees,
    const int* __restrict__ choices,
    int* __restrict__ out, int n,
    const int* __restrict__ flag) {

    int w = blockIdx.x * blockDim.x + threadIdx.x;
    if (w >= n) return;

    int* walks      = out;                    // [STEPS+1, n]
    int* walk_edges = out + (STEPS + 1) * n;  // [STEPS, n]
    walks[w] = w;

    if (*flag == 0) {
        // ---- fast path: uniform CSR, deg=16 ----
        // Preload all choices (independent coalesced loads, hidden early).
        int chs[STEPS];
#pragma unroll
        for (int i = 0; i < STEPS; ++i) chs[i] = choices[i * n + w];

        int prev = -1, cur = w;
#pragma unroll
        for (int i = 0; i < STEPS; ++i) {
            int ch   = chs[i];
            int e    = ch & (DEG - 1);
            int base = cur << 4;                         // cur * DEG
            int chosen = base + e;
            int alt    = base + ((e + 1 + ch % (DEG - 1)) & (DEG - 1));

            int nw0 = adj_nodes[chosen];   // same 64B line as alt
            int nw1 = adj_nodes[alt];

            bool bt = (nw0 == prev);
            int nw  = bt ? nw1 : nw0;
            walks[(i + 1) * n + w] = nw;
            walk_edges[i * n + w]  = bt ? alt : chosen;
            prev = cur;
            cur  = nw;
        }
    } else {
        // ---- general fallback (2 dependent gathers per step) ----
        int prev = -1, cur = w;
        for (int i = 0; i < STEPS; ++i) {
            int ch  = choices[i * n + w];
            int deg = degrees[cur];
            int off = adj_offset[cur];
            int nb  = deg - 1 > 1 ? deg - 1 : 1;

            int e      = ch % deg;
            int chosen = off + e;
            int alt    = off + (e + 1 + ch % nb) % deg;

            int nw0 = adj_nodes[chosen];
            int nw1 = adj_nodes[alt];

            bool bt = (nw0 == prev);
            int nw  = bt ? nw1 : nw0;
            walks[(i + 1) * n + w] = nw;
            walk_edges[i * n + w]  = bt ? alt : chosen;
            prev = cur;
            cur  = nw;
        }
    }
}

__global__ __launch_bounds__(256) void walker_generic(
    const int* __restrict__ adj_nodes,
    const int* __restrict__ adj_offset,
    const int* __restrict__ degrees,
    const int* __restrict__ choices,
    int* __restrict__ out, int n, int steps) {

    int w = blockIdx.x * blockDim.x + threadIdx.x;
    if (w >= n) return;

    int* walks      = out;
    int* walk_edges = out + (steps + 1) * n;
    walks[w] = w;

    int prev = -1, cur = w;
    for (int i = 0; i < steps; ++i) {
        int ch  = choices[i * n + w];
        int deg = degrees[cur];
        int off = adj_offset[cur];
        int nb  = deg - 1 > 1 ? deg - 1 : 1;

        int e      = ch % deg;
        int chosen = off + e;
        int alt    = off + (e + 1 + ch % nb) % deg;

        int nw0 = adj_nodes[chosen];
        int nw1 = adj_nodes[alt];

        bool bt = (nw0 == prev);
        int nw  = bt ? nw1 : nw0;
        walks[(i + 1) * n + w] = nw;
        walk_edges[i * n + w]  = bt ? alt : chosen;
        prev = cur;
        cur  = nw;
    }
}

extern "C" void kernel_launch(void* const* d_in, const int* in_sizes, int n_in,
                              void* d_out, int out_size, void* d_ws, size_t ws_size,
                              hipStream_t stream) {
    // inputs: 0=x (unused), 1=adj_nodes, 2=adj_offset, 3=degrees, 4=choices
    const int* adj_nodes  = (const int*)d_in[1];
    const int* adj_offset = (const int*)d_in[2];
    const int* degrees    = (const int*)d_in[3];
    const int* choices    = (const int*)d_in[4];
    int* out  = (int*)d_out;
    int* flag = (int*)d_ws;

    int n     = in_sizes[2];
    int steps = in_sizes[4] / n;

    int block = 256;
    int grid  = (n + block - 1) / block;

    if (steps == 32) {
        hipMemsetAsync(flag, 0, sizeof(int), stream);
        check_kernel<<<grid, block, 0, stream>>>(degrees, adj_offset, n, flag);
        walker_fast<32><<<grid, block, 0, stream>>>(adj_nodes, adj_offset,
                                                    degrees, choices, out, n, flag);
    } else {
        walker_generic<<<grid, block, 0, stream>>>(adj_nodes, adj_offset,
                                                   degrees, choices, out, n, steps);
    }
}